// Round 14
// baseline (6983.732 us; speedup 1.0000x reference)
//
#include <hip/hip_runtime.h>
#include <hip/hip_bf16.h>
#include <cstdint>

typedef __bf16 bf16_t;
typedef __bf16 bf16x4 __attribute__((ext_vector_type(4)));
typedef __bf16 bf16x8 __attribute__((ext_vector_type(8)));
typedef float f32x4 __attribute__((ext_vector_type(4)));

#define BATCH 4096
#define DIN   1024
#define HID   2048
#define DOUT  1000
#define NITER 50
#define LR    0.001f

#define BM 128
#define BN 128
#define BK 32
#define NBUF 4

// async global -> LDS, 16 B per lane. LDS dest is wave-uniform base + lane*16.
#define GLDS(g, l)                                                        \
    __builtin_amdgcn_global_load_lds(                                     \
        (const __attribute__((address_space(1))) void*)(g),               \
        (__attribute__((address_space(3))) void*)(l), 16, 0, 0)

#define WAITVM(N) asm volatile("s_waitcnt vmcnt(" #N ")" ::: "memory")
#define BAR()     __builtin_amdgcn_s_barrier()
#define SCHEDB()  __builtin_amdgcn_sched_barrier(0)

// ---------------------------------------------------------------------------
// Persistent kernel, MEMORY state (R7's proven per-iter structure: u,z f32 +
// ey bf16 in global; 52-VGPR-class GEMM core) + slice barrier (R13-proven)
// instead of 50 launches.  R9-R13 lesson: register-state costs ~50 regs ->
// kills the 2-blocks/CU occupancy worth more than the state traffic.
// Grid = 512 blocks x 512 thr, 8 waves, wave tile 64x32 acc[4][2], LDS
// 64.5 KB -> 2 blocks/CU (16 waves/CU, two independent barrier groups).
// XCD swizzle (m-ownership): p -> r=p&7 (XCD), k=p>>3; m = 4r + (k>>4),
// sub = k&15 (sub<8: U role Bt=Wg; sub>=8: Z role Bt=Wc).  Each XCD owns
// 4 m-slices for ALL n-panels -> e_x/x/u/z/ey panels XCD-local (kills the
// e_x broadcast = R7's 57 MB/iter HBM); weights broadcast but L3-resident.
// Slice m's 16 blocks are p = r + 8*((m&3)*16 + sub): contiguous 128-band ->
// partial-residency fallback (R13) cannot deadlock.
//   U: u[idx] += LR*D (f32, global); e_x' = x - sigmoid(u) -> Adst; energy
//   Z: z += LR*D; e_y' = (1+LR)e_y - LR*D (bf16); last iter y = (1+LR)e_y + z
// K-loop: NBUF=4, 2 K-tiles/barrier-pair, counted vmcnt (4 steady, ->0 tail).
// ---------------------------------------------------------------------------
__global__ __launch_bounds__(512) void pc_persist(
    bf16_t* __restrict__ exA, bf16_t* __restrict__ exB,
    const bf16_t* __restrict__ wg, const bf16_t* __restrict__ wc,
    const float* __restrict__ xin, const float* __restrict__ bias_g,
    const float* __restrict__ bias_o,
    float* __restrict__ u, float* __restrict__ z, bf16_t* __restrict__ ey,
    float* __restrict__ yout, float* __restrict__ energy,
    unsigned int* __restrict__ barcnt)
{
    __shared__ __align__(16) bf16_t sA[NBUF][BM * BK];
    __shared__ __align__(16) bf16_t sB[NBUF][BN * BK];
    __shared__ float red[8];

    const int t    = threadIdx.x;
    const int lane = t & 63;
    const int wave = t >> 6;        // 0..7
    const int wm   = wave >> 2;     // 0..1 -> 64 rows
    const int wn   = wave & 3;      // 0..3 -> 32 cols
    const int p    = blockIdx.x;
    const int r    = p & 7;         // XCD under round-robin
    const int k    = p >> 3;        // 0..63
    const int m    = (r << 2) | (k >> 4);   // 0..31: XCD r owns m=4r..4r+3
    const int sub  = k & 15;
    const int role = sub >> 3;      // 0 = U (e_x side), 1 = Z (y side)
    const int n0   = (sub & 7) * BN;
    const int m0   = m * BM;
    const int lr   = lane & 15;
    const int lkb  = (lane >> 4) * 8;
    const int prow = (lane >> 4) * 4;

    const int srow = wave * 16 + (lane >> 2);
    const int scol = (lane & 3) * 8;
    const bf16_t* gB = (role ? wc : wg) + (int64_t)(n0 + srow) * DIN + scol;

    float esum = 0.0f;
    const bf16_t* Asrc = exA;
    bf16_t*       Adst = exB;

    for (int it = 0; it < NITER; ++it) {
        const bool active = !(it == NITER - 1 && role == 0);
        if (active) {
            const bf16_t* gA = Asrc + (int64_t)(m0 + srow) * DIN + scol;
            f32x4 acc[4][2] = {};

            auto stage = [&](int tile, int buf) {
                const int64_t ko = (int64_t)tile * BK;
                GLDS(gA + ko, &sA[buf][wave * 512]);
                GLDS(gB + ko, &sB[buf][wave * 512]);
            };
            auto compute = [&](int buf) {
                bf16x8 af[4], bfr[2];
#pragma unroll
                for (int mi = 0; mi < 4; ++mi)
                    af[mi] = *reinterpret_cast<const bf16x8*>(
                        &sA[buf][(wm * 64 + mi * 16 + lr) * BK + lkb]);
#pragma unroll
                for (int ni = 0; ni < 2; ++ni)
                    bfr[ni] = *reinterpret_cast<const bf16x8*>(
                        &sB[buf][(wn * 32 + ni * 16 + lr) * BK + lkb]);
#pragma unroll
                for (int mi = 0; mi < 4; ++mi)
#pragma unroll
                    for (int ni = 0; ni < 2; ++ni)
                        acc[mi][ni] = __builtin_amdgcn_mfma_f32_16x16x32_bf16(
                            af[mi], bfr[ni], acc[mi][ni], 0, 0, 0);
            };

            const int npairs = (DIN / BK) / 2;   // 16
            stage(0, 0); stage(1, 1); stage(2, 2); stage(3, 3);  // 8 loads
            for (int pp = 0; pp < npairs - 2; ++pp) {
                const int t0 = 2 * pp;
                WAITVM(4);                 // pair pp landed; pair pp+1 flying
                BAR();
                SCHEDB();
                compute(t0 & 3);
                compute((t0 + 1) & 3);
                BAR();
                stage(t0 + 4, t0 & 3);     // back to 8 in flight; never 0
                stage(t0 + 5, (t0 + 1) & 3);
            }
            {
                const int t0 = 2 * npairs - 4;
                WAITVM(4); BAR(); SCHEDB();
                compute(t0 & 3); compute((t0 + 1) & 3);
            }
            {
                const int t0 = 2 * npairs - 2;
                WAITVM(0); BAR(); SCHEDB();
                compute(t0 & 3); compute((t0 + 1) & 3);
            }

            // epilogue: C mapping col=lane&15, row=(lane>>4)*4+j
#pragma unroll
            for (int mi = 0; mi < 4; ++mi) {
#pragma unroll
                for (int ni = 0; ni < 2; ++ni) {
                    const int col = n0 + wn * 32 + ni * 16 + lr;
#pragma unroll
                    for (int j = 0; j < 4; ++j) {
                        const int row = m0 + wm * 64 + mi * 16 + prow + j;
                        const float D = LR * acc[mi][ni][j];
                        if (role == 0) {
                            const int64_t idx = (int64_t)row * DIN + col;
                            const float base = (it == 0) ? bias_g[col]
                                                         : u[idx];
                            const float un = base + D;
                            u[idx] = un;
                            const float xp = 1.0f / (1.0f + __expf(-un));
                            const float e  = xin[idx] - xp;
                            Adst[idx] = (bf16_t)e;
                            esum += e * e;
                        } else if (col < DOUT) {
                            const int64_t idx = (int64_t)row * 1024 + col;
                            const float base = (it == 0) ? bias_o[col]
                                                         : z[idx];
                            const float zn = base + D;
                            const float eyn = (it == 0)
                                ? -zn
                                : (1.0f + LR) * (float)ey[idx] - D;
                            if (it == NITER - 1) {
                                yout[(int64_t)row * DOUT + col] =
                                    (1.0f + LR) * eyn + zn;
                            } else {
                                z[idx]  = zn;
                                ey[idx] = (bf16_t)eyn;
                            }
                            esum += eyn * eyn;
                        }
                    }
                }
            }
        }

        // ---- slice barrier: 16 blocks sharing m-slice, monotonic counter ---
        if (it != NITER - 1) {
            __syncthreads();
            if (t == 0) {
                __threadfence();                       // publish e_x' stores
                atomicAdd(&barcnt[m], 1u);
                const unsigned int tgt = 16u * (unsigned int)(it + 1);
                while (atomicAdd(&barcnt[m], 0u) < tgt)
                    __builtin_amdgcn_s_sleep(8);
                __threadfence();                       // acquire peers' stores
            }
            __syncthreads();
        }
        bf16_t* tmp = Adst; Adst = (bf16_t*)Asrc; Asrc = tmp;
    }

    // energy reduction: esum accumulated over all iterations
#pragma unroll
    for (int off = 32; off; off >>= 1) esum += __shfl_down(esum, off, 64);
    if (lane == 0) red[wave] = esum;
    __syncthreads();
    if (t == 0) {
        float s = 0.0f;
#pragma unroll
        for (int w = 0; w < 8; ++w) s += red[w];
        atomicAdd(energy, s);
    }
}

// ---------------------------------------------------------------------------
// setup: Wg = W_rec^T W_rec (role 0), Wc = W_out W_rec (role 1); K = 2048.
// R6-proven GEMM core, plain C-store epilogue.  Runs once.
// ---------------------------------------------------------------------------
__global__ __launch_bounds__(512) void setup_gemm(
    const bf16_t* __restrict__ wrecT, const bf16_t* __restrict__ woutP,
    bf16_t* __restrict__ wg, bf16_t* __restrict__ wc)
{
    __shared__ __align__(16) bf16_t sA[NBUF][BM * BK];
    __shared__ __align__(16) bf16_t sB[NBUF][BN * BK];

    const int t    = threadIdx.x;
    const int lane = t & 63;
    const int wave = t >> 6;
    const int wm   = wave >> 2;
    const int wn   = wave & 3;
    const int m0   = blockIdx.x * BM;
    const int role = (int)blockIdx.y >= 8;
    const int n0   = ((int)blockIdx.y & 7) * BN;
    const int lr   = lane & 15;
    const int lkb  = (lane >> 4) * 8;
    const int prow = (lane >> 4) * 4;

    f32x4 acc[4][2] = {};

    const int srow = wave * 16 + (lane >> 2);
    const int scol = (lane & 3) * 8;
    const bf16_t* gA = (role ? woutP : wrecT) + (int64_t)(m0 + srow) * HID + scol;
    const bf16_t* gB = wrecT + (int64_t)(n0 + srow) * HID + scol;

    auto stage = [&](int tile, int buf) {
        const int64_t ko = (int64_t)tile * BK;
        GLDS(gA + ko, &sA[buf][wave * 512]);
        GLDS(gB + ko, &sB[buf][wave * 512]);
    };
    auto compute = [&](int buf) {
        bf16x8 af[4], bfr[2];
#pragma unroll
        for (int mi = 0; mi < 4; ++mi)
            af[mi] = *reinterpret_cast<const bf16x8*>(
                &sA[buf][(wm * 64 + mi * 16 + lr) * BK + lkb]);
#pragma unroll
        for (int ni = 0; ni < 2; ++ni)
            bfr[ni] = *reinterpret_cast<const bf16x8*>(
                &sB[buf][(wn * 32 + ni * 16 + lr) * BK + lkb]);
#pragma unroll
        for (int mi = 0; mi < 4; ++mi)
#pragma unroll
            for (int ni = 0; ni < 2; ++ni)
                acc[mi][ni] = __builtin_amdgcn_mfma_f32_16x16x32_bf16(
                    af[mi], bfr[ni], acc[mi][ni], 0, 0, 0);
    };

    const int npairs = (HID / BK) / 2;   // 32
    stage(0, 0); stage(1, 1); stage(2, 2); stage(3, 3);
    for (int p = 0; p < npairs - 2; ++p) {
        const int t0 = 2 * p;
        WAITVM(4); BAR(); SCHEDB();
        compute(t0 & 3); compute((t0 + 1) & 3);
        BAR();
        stage(t0 + 4, t0 & 3); stage(t0 + 5, (t0 + 1) & 3);
    }
    {
        const int t0 = 2 * npairs - 4;
        WAITVM(4); BAR(); SCHEDB();
        compute(t0 & 3); compute((t0 + 1) & 3);
    }
    {
        const int t0 = 2 * npairs - 2;
        WAITVM(0); BAR(); SCHEDB();
        compute(t0 & 3); compute((t0 + 1) & 3);
    }

    bf16_t* cout = role ? wc : wg;
#pragma unroll
    for (int mi = 0; mi < 4; ++mi)
#pragma unroll
        for (int ni = 0; ni < 2; ++ni) {
            const int col = n0 + wn * 32 + ni * 16 + lr;
#pragma unroll
            for (int j = 0; j < 4; ++j) {
                const int row = m0 + wm * 64 + mi * 16 + prow + j;
                cout[(int64_t)row * 1024 + col] = (bf16_t)acc[mi][ni][j];
            }
        }
}

// W_rec [HID][DIN] f32 -> bf16 transpose [DIN][HID]
__global__ void conv_wrec(const float* __restrict__ W, bf16_t* __restrict__ WbT)
{
    __shared__ float tile[32][33];
    const int tx = threadIdx.x & 31;
    const int ty = threadIdx.x >> 5;
    const int c0 = blockIdx.x * 32;
    const int r0 = blockIdx.y * 32;
#pragma unroll
    for (int rr = ty; rr < 32; rr += 8)
        tile[rr][tx] = W[(int64_t)(r0 + rr) * DIN + c0 + tx];
    __syncthreads();
#pragma unroll
    for (int rr = ty; rr < 32; rr += 8)
        WbT[(int64_t)(c0 + rr) * HID + r0 + tx] = (bf16_t)tile[tx][rr];
}

// W_out [DOUT][HID] f32 -> bf16 [1024][HID], rows >= DOUT zero-padded
__global__ void conv_wout(const float* __restrict__ W, bf16_t* __restrict__ Wb)
{
    const int i = blockIdx.x * 256 + threadIdx.x;
    const int r = i >> 11;
    const int c = i & 2047;
    Wb[i] = (r < DOUT) ? (bf16_t)W[(int64_t)r * HID + c] : (bf16_t)0.0f;
}

// iteration 0: e_x_0 = x - sigmoid(b_gen), + its energy term
__global__ void ex0_kernel(const float* __restrict__ x,
                           const float* __restrict__ bias_g,
                           bf16_t* __restrict__ ex, float* __restrict__ energy)
{
    __shared__ float red[4];
    const int t = threadIdx.x, lane = t & 63, wave = t >> 6;
    const int i = (blockIdx.x * 256 + t) * 4;
    const int c0 = i & (DIN - 1);
    const float4 v = *reinterpret_cast<const float4*>(&x[i]);
    float e[4];
    const float b0 = bias_g[c0], b1 = bias_g[c0 + 1],
                b2 = bias_g[c0 + 2], b3 = bias_g[c0 + 3];
    e[0] = v.x - 1.0f / (1.0f + __expf(-b0));
    e[1] = v.y - 1.0f / (1.0f + __expf(-b1));
    e[2] = v.z - 1.0f / (1.0f + __expf(-b2));
    e[3] = v.w - 1.0f / (1.0f + __expf(-b3));
    bf16x4 o = {(bf16_t)e[0], (bf16_t)e[1], (bf16_t)e[2], (bf16_t)e[3]};
    *reinterpret_cast<bf16x4*>(&ex[i]) = o;
    float esum = e[0]*e[0] + e[1]*e[1] + e[2]*e[2] + e[3]*e[3];
#pragma unroll
    for (int off = 32; off; off >>= 1) esum += __shfl_down(esum, off, 64);
    if (lane == 0) red[wave] = esum;
    __syncthreads();
    if (t == 0) atomicAdd(energy, red[0] + red[1] + red[2] + red[3]);
}

__global__ void finalize_kernel(const float* __restrict__ energy,
                                float* __restrict__ out)
{
    out[0] = energy[0] * (1.0f / ((float)BATCH * (float)NITER));
}

extern "C" void kernel_launch(void* const* d_in, const int* in_sizes, int n_in,
                              void* d_out, int out_size, void* d_ws, size_t ws_size,
                              hipStream_t stream)
{
    (void)in_sizes; (void)n_in; (void)out_size; (void)ws_size;
    const float* x        = (const float*)d_in[0];
    const float* W_rec    = (const float*)d_in[1];
    const float* W_out    = (const float*)d_in[2];
    const float* bias_out = (const float*)d_in[3];
    const float* bias_gen = (const float*)d_in[4];
    float* y = (float*)d_out; // [BATCH*DOUT] then [1] energy

    char* ws = (char*)d_ws;
    size_t off = 0;
    float* u      = (float*)(ws + off);   off += (size_t)BATCH * DIN * 4;   // 16 MB
    float* z      = (float*)(ws + off);   off += (size_t)BATCH * 1024 * 4;  // 16 MB
    bf16_t* ey    = (bf16_t*)(ws + off);  off += (size_t)BATCH * 1024 * 2;  //  8 MB
    bf16_t* exA   = (bf16_t*)(ws + off);  off += (size_t)BATCH * DIN * 2;   //  8 MB
    bf16_t* exB   = (bf16_t*)(ws + off);  off += (size_t)BATCH * DIN * 2;   //  8 MB
    bf16_t* wrecT = (bf16_t*)(ws + off);  off += (size_t)DIN * HID * 2;     //  4 MB
    bf16_t* woutP = (bf16_t*)(ws + off);  off += (size_t)1024 * HID * 2;    //  4 MB
    bf16_t* wg    = (bf16_t*)(ws + off);  off += (size_t)1024 * 1024 * 2;   //  2 MB
    bf16_t* wc    = (bf16_t*)(ws + off);  off += (size_t)1024 * 1024 * 2;   //  2 MB
    float* energy = (float*)(ws + off);                                     // +256 B
    unsigned int* barcnt = (unsigned int*)(ws + off + 64);  // 32 counters

    // zero energy + barrier counters (fresh every call -> deterministic)
    hipMemsetAsync(energy, 0, 256, stream);

    conv_wrec<<<dim3(DIN / 32, HID / 32), 256, 0, stream>>>(W_rec, wrecT);
    conv_wout<<<(1024 * HID) / 256, 256, 0, stream>>>(W_out, woutP);
    setup_gemm<<<dim3(8, 16), 512, 0, stream>>>(wrecT, woutP, wg, wc);
    ex0_kernel<<<(BATCH * DIN) / 1024, 256, 0, stream>>>(x, bias_gen, exA, energy);

    pc_persist<<<dim3(512), dim3(512), 0, stream>>>(
        exA, exB, wg, wc, x, bias_gen, bias_out, u, z, ey, y, energy, barcnt);

    finalize_kernel<<<1, 1, 0, stream>>>(energy, y + (size_t)BATCH * DOUT);
}

// Round 15
// 1852.544 us; speedup vs baseline: 3.7698x; 3.7698x over previous
//
#include <hip/hip_runtime.h>
#include <hip/hip_bf16.h>
#include <cstdint>

typedef __bf16 bf16_t;
typedef __bf16 bf16x4 __attribute__((ext_vector_type(4)));
typedef __bf16 bf16x8 __attribute__((ext_vector_type(8)));
typedef float f32x4 __attribute__((ext_vector_type(4)));

#define BATCH 4096
#define DIN   1024
#define HID   2048
#define DOUT  1000
#define NITER 50
#define LR    0.001f

#define BM 128
#define BN 128
#define BK 32
#define NBUF 4

// async global -> LDS, 16 B per lane. LDS dest is wave-uniform base + lane*16.
#define GLDS(g, l)                                                        \
    __builtin_amdgcn_global_load_lds(                                     \
        (const __attribute__((address_space(1))) void*)(g),               \
        (__attribute__((address_space(3))) void*)(l), 16, 0, 0)

#define WAITVM(N) asm volatile("s_waitcnt vmcnt(" #N ")" ::: "memory")
#define BAR()     __builtin_amdgcn_s_barrier()
#define SCHEDB()  __builtin_amdgcn_sched_barrier(0)

// ---------------------------------------------------------------------------
// R7 champion structure (2020 us measured), states converted to bf16.
// Reformulated predictive-coding step (h eliminated):
//   u += LR * (e_x @ Wg)   [Wg = W_rec^T W_rec, symmetric]
//   z += LR * (e_x @ Wc^T) [Wc = W_out W_rec]
//   e_x' = x - sigmoid(u)   (U epilogue);  e_y' = (1+LR)e_y - D (Z epilogue)
//   y_final = (1+LR)e_y + z (MODE 2)
// One GEMM dispatch per iteration: A = e_x (bf16 ping-pong), K = 1024,
// grid 32x16: blockIdx.y<8 -> U role (Bt=Wg), >=8 -> Z role (Bt=Wc).
// GEMM core = R6-proven: 512 thr / 8 waves (2x4), wave tile 64x32 acc[4][2],
// 4 LDS buffers, two K-tiles per barrier pair, counted vmcnt (T4).
// bf16 states (u, z, ey, xbf): numerically safe (increments >> bf16
// resolution at state scale; 50-step quantization walk ~6e-4 << threshold).
// MODE: 0 = UZ, 1 = UZ first (seed from biases), 2 = Z-only final (writes y),
//       3 = setup (Wg | Wc), K = 2048.
// ---------------------------------------------------------------------------
template <int MODE>
__global__ __launch_bounds__(512) void pc_gemm(
    const bf16_t* __restrict__ Aex, bf16_t* __restrict__ wrecT,
    bf16_t* __restrict__ woutP, bf16_t* __restrict__ wg,
    bf16_t* __restrict__ wc,
    const bf16_t* __restrict__ xbf, const float* __restrict__ bias_g,
    const float* __restrict__ bias_o,
    bf16_t* __restrict__ exnext, bf16_t* __restrict__ u,
    bf16_t* __restrict__ z, bf16_t* __restrict__ ey,
    float* __restrict__ yout, float* __restrict__ energy)
{
    __shared__ __align__(16) bf16_t sA[NBUF][BM * BK];
    __shared__ __align__(16) bf16_t sB[NBUF][BN * BK];
    __shared__ float red[8];

    const int t    = threadIdx.x;
    const int lane = t & 63;
    const int wave = t >> 6;        // 0..7
    const int wm   = wave >> 2;     // wave row (0..1) -> 64 rows
    const int wn   = wave & 3;      // wave col (0..3) -> 32 cols
    const int m0   = blockIdx.x * BM;
    const int lr   = lane & 15;
    const int lkb  = (lane >> 4) * 8;

    int role, n0, K;
    const bf16_t *Aop, *Bop;
    if constexpr (MODE == 3) {
        role = (int)blockIdx.y >= 8; n0 = ((int)blockIdx.y & 7) * BN; K = HID;
        Aop = role ? woutP : wrecT;  Bop = wrecT;
    } else if constexpr (MODE == 2) {
        role = 1; n0 = (int)blockIdx.y * BN; K = DIN;
        Aop = Aex; Bop = wc;
    } else {
        role = (int)blockIdx.y >= 8; n0 = ((int)blockIdx.y & 7) * BN; K = DIN;
        Aop = Aex; Bop = role ? wc : wg;
    }

    f32x4 acc[4][2] = {};

    // staging: lane l of wave w -> tile row w*16 + l/4, col chunk (l&3)*8
    const int srow = wave * 16 + (lane >> 2);
    const int scol = (lane & 3) * 8;
    const bf16_t* gA = Aop + (int64_t)(m0 + srow) * K + scol;
    const bf16_t* gB = Bop + (int64_t)(n0 + srow) * K + scol;

    auto stage = [&](int tile, int buf) {
        const int64_t ko = (int64_t)tile * BK;
        GLDS(gA + ko, &sA[buf][wave * 512]);
        GLDS(gB + ko, &sB[buf][wave * 512]);
    };

    auto compute = [&](int buf) {
        bf16x8 af[4], bfr[2];
#pragma unroll
        for (int mi = 0; mi < 4; ++mi)
            af[mi] = *reinterpret_cast<const bf16x8*>(
                &sA[buf][(wm * 64 + mi * 16 + lr) * BK + lkb]);
#pragma unroll
        for (int ni = 0; ni < 2; ++ni)
            bfr[ni] = *reinterpret_cast<const bf16x8*>(
                &sB[buf][(wn * 32 + ni * 16 + lr) * BK + lkb]);
#pragma unroll
        for (int mi = 0; mi < 4; ++mi)
#pragma unroll
            for (int ni = 0; ni < 2; ++ni)
                acc[mi][ni] = __builtin_amdgcn_mfma_f32_16x16x32_bf16(
                    af[mi], bfr[ni], acc[mi][ni], 0, 0, 0);
    };

    const int npairs = (K / BK) / 2;       // 16 (UZ) or 32 (setup)
    stage(0, 0); stage(1, 1); stage(2, 2); stage(3, 3);

    for (int p = 0; p < npairs - 2; ++p) {
        const int t0 = 2 * p;
        WAITVM(4);               // pair p landed; pair p+1 still flying
        BAR();
        SCHEDB();
        compute(t0 & 3);
        compute((t0 + 1) & 3);
        BAR();
        stage(t0 + 4, t0 & 3);   // vmcnt never drains to 0 in loop
        stage(t0 + 5, (t0 + 1) & 3);
    }
    {
        const int t0 = 2 * npairs - 4;
        WAITVM(4); BAR(); SCHEDB();
        compute(t0 & 3); compute((t0 + 1) & 3);
    }
    {
        const int t0 = 2 * npairs - 2;
        WAITVM(0); BAR(); SCHEDB();
        compute(t0 & 3); compute((t0 + 1) & 3);
    }

    // epilogue: C mapping col=lane&15, row=(lane>>4)*4+j
    float esum = 0.0f;
    const int prow = (lane >> 4) * 4;
#pragma unroll
    for (int mi = 0; mi < 4; ++mi) {
#pragma unroll
        for (int ni = 0; ni < 2; ++ni) {
            const int col = n0 + wn * 32 + ni * 16 + lr;
#pragma unroll
            for (int j = 0; j < 4; ++j) {
                const int row = m0 + wm * 64 + mi * 16 + prow + j;
                const float v = acc[mi][ni][j];
                if constexpr (MODE == 3) {
                    bf16_t* cout = role ? wc : wg;
                    cout[(int64_t)row * 1024 + col] = (bf16_t)v;
                } else {
                    if (role == 0) {
                        // U role: u += LR*v; e_x' = x - sigmoid(u); energy
                        const int64_t idx = (int64_t)row * DIN + col;
                        const float D  = LR * v;
                        const float un =
                            (MODE == 1 ? bias_g[col] : (float)u[idx]) + D;
                        u[idx] = (bf16_t)un;
                        const float xp = 1.0f / (1.0f + __expf(-un));
                        const float e  = (float)xbf[idx] - xp;
                        exnext[idx] = (bf16_t)e;
                        esum += e * e;
                    } else if (col < DOUT) {
                        // Z role: z += D; e_y = (1+LR)e_y - D; energy
                        const int64_t idx = (int64_t)row * 1024 + col;
                        const float D  = LR * v;
                        const float zn =
                            (MODE == 1 ? bias_o[col] : (float)z[idx]) + D;
                        const float eyn = (MODE == 1)
                            ? -zn
                            : (1.0f + LR) * (float)ey[idx] - D;
                        if constexpr (MODE == 2) {
                            yout[(int64_t)row * DOUT + col] =
                                (1.0f + LR) * eyn + zn;
                        } else {
                            z[idx]  = (bf16_t)zn;
                            ey[idx] = (bf16_t)eyn;
                        }
                        esum += eyn * eyn;
                    }
                }
            }
        }
    }
    if constexpr (MODE != 3) {
#pragma unroll
        for (int off = 32; off; off >>= 1) esum += __shfl_down(esum, off, 64);
        if (lane == 0) red[wave] = esum;
        __syncthreads();
        if (t == 0) {
            float s = 0.0f;
#pragma unroll
            for (int w = 0; w < 8; ++w) s += red[w];
            atomicAdd(energy, s);
        }
    }
}

// W_rec [HID][DIN] f32 -> bf16 transpose [DIN][HID]
__global__ void conv_wrec(const float* __restrict__ W, bf16_t* __restrict__ WbT)
{
    __shared__ float tile[32][33];
    const int tx = threadIdx.x & 31;
    const int ty = threadIdx.x >> 5; // 0..7
    const int c0 = blockIdx.x * 32;  // DIN
    const int r0 = blockIdx.y * 32;  // HID
#pragma unroll
    for (int rr = ty; rr < 32; rr += 8)
        tile[rr][tx] = W[(int64_t)(r0 + rr) * DIN + c0 + tx];
    __syncthreads();
#pragma unroll
    for (int rr = ty; rr < 32; rr += 8)
        WbT[(int64_t)(c0 + rr) * HID + r0 + tx] = (bf16_t)tile[tx][rr];
}

// W_out [DOUT][HID] f32 -> bf16 [1024][HID], rows >= DOUT zero-padded
__global__ void conv_wout(const float* __restrict__ W, bf16_t* __restrict__ Wb)
{
    const int i = blockIdx.x * 256 + threadIdx.x; // over 1024*2048
    const int r = i >> 11;
    const int c = i & 2047;
    Wb[i] = (r < DOUT) ? (bf16_t)W[(int64_t)r * HID + c] : (bf16_t)0.0f;
}

// iteration 0: e_x0 = x - sigmoid(b_gen) (+ energy); also x -> bf16 copy
__global__ void ex0_kernel(const float* __restrict__ x,
                           const float* __restrict__ bias_g,
                           bf16_t* __restrict__ ex, bf16_t* __restrict__ xbf,
                           float* __restrict__ energy)
{
    __shared__ float red[4];
    const int t = threadIdx.x, lane = t & 63, wave = t >> 6;
    const int i = (blockIdx.x * 256 + t) * 4;
    const int c0 = i & (DIN - 1);
    const float4 v = *reinterpret_cast<const float4*>(&x[i]);
    bf16x4 xo = {(bf16_t)v.x, (bf16_t)v.y, (bf16_t)v.z, (bf16_t)v.w};
    *reinterpret_cast<bf16x4*>(&xbf[i]) = xo;
    float e[4];
    const float b0 = bias_g[c0], b1 = bias_g[c0 + 1],
                b2 = bias_g[c0 + 2], b3 = bias_g[c0 + 3];
    e[0] = v.x - 1.0f / (1.0f + __expf(-b0));
    e[1] = v.y - 1.0f / (1.0f + __expf(-b1));
    e[2] = v.z - 1.0f / (1.0f + __expf(-b2));
    e[3] = v.w - 1.0f / (1.0f + __expf(-b3));
    bf16x4 o = {(bf16_t)e[0], (bf16_t)e[1], (bf16_t)e[2], (bf16_t)e[3]};
    *reinterpret_cast<bf16x4*>(&ex[i]) = o;
    float esum = e[0]*e[0] + e[1]*e[1] + e[2]*e[2] + e[3]*e[3];
#pragma unroll
    for (int off = 32; off; off >>= 1) esum += __shfl_down(esum, off, 64);
    if (lane == 0) red[wave] = esum;
    __syncthreads();
    if (t == 0) atomicAdd(energy, red[0] + red[1] + red[2] + red[3]);
}

__global__ void finalize_kernel(const float* __restrict__ energy,
                                float* __restrict__ out)
{
    out[0] = energy[0] * (1.0f / ((float)BATCH * (float)NITER));
}

extern "C" void kernel_launch(void* const* d_in, const int* in_sizes, int n_in,
                              void* d_out, int out_size, void* d_ws, size_t ws_size,
                              hipStream_t stream)
{
    (void)in_sizes; (void)n_in; (void)out_size; (void)ws_size;
    const float* x        = (const float*)d_in[0];
    const float* W_rec    = (const float*)d_in[1];
    const float* W_out    = (const float*)d_in[2];
    const float* bias_out = (const float*)d_in[3];
    const float* bias_gen = (const float*)d_in[4];
    float* y = (float*)d_out; // [BATCH*DOUT] then [1] energy

    char* ws = (char*)d_ws;
    size_t off = 0;
    bf16_t* u     = (bf16_t*)(ws + off);  off += (size_t)BATCH * DIN * 2;   // 8 MB
    bf16_t* z     = (bf16_t*)(ws + off);  off += (size_t)BATCH * 1024 * 2;  // 8 MB
    bf16_t* exA   = (bf16_t*)(ws + off);  off += (size_t)BATCH * DIN * 2;   // 8 MB
    bf16_t* exB   = (bf16_t*)(ws + off);  off += (size_t)BATCH * DIN * 2;   // 8 MB
    bf16_t* ey    = (bf16_t*)(ws + off);  off += (size_t)BATCH * 1024 * 2;  // 8 MB
    bf16_t* xbf   = (bf16_t*)(ws + off);  off += (size_t)BATCH * DIN * 2;   // 8 MB
    bf16_t* wrecT = (bf16_t*)(ws + off);  off += (size_t)DIN * HID * 2;     // 4 MB
    bf16_t* woutP = (bf16_t*)(ws + off);  off += (size_t)1024 * HID * 2;    // 4 MB
    bf16_t* wg    = (bf16_t*)(ws + off);  off += (size_t)1024 * 1024 * 2;   // 2 MB
    bf16_t* wc    = (bf16_t*)(ws + off);  off += (size_t)1024 * 1024 * 2;   // 2 MB
    float* energy = (float*)(ws + off);   off += 256;                       // 60 MB

    hipMemsetAsync(energy, 0, 4, stream);

    conv_wrec<<<dim3(DIN / 32, HID / 32), 256, 0, stream>>>(W_rec, wrecT);
    conv_wout<<<(1024 * HID) / 256, 256, 0, stream>>>(W_out, woutP);
    // setup: Wg = W_rec^T W_rec (y<8), Wc = W_out W_rec (y>=8), K = 2048
    pc_gemm<3><<<dim3(8, 16), 512, 0, stream>>>(
        nullptr, wrecT, woutP, wg, wc, nullptr, nullptr, nullptr,
        nullptr, nullptr, nullptr, nullptr, nullptr, nullptr);

    ex0_kernel<<<(BATCH * DIN) / 1024, 256, 0, stream>>>(x, bias_gen, exA,
                                                         xbf, energy);

    bf16_t* exbuf[2] = {exA, exB};
    for (int it = 0; it < NITER; ++it) {
        const bf16_t* src = exbuf[it & 1];
        bf16_t* dst = exbuf[(it & 1) ^ 1];
        if (it == 0)
            pc_gemm<1><<<dim3(BATCH / BM, 16), 512, 0, stream>>>(
                src, nullptr, nullptr, wg, wc, xbf, bias_gen, bias_out,
                dst, u, z, ey, nullptr, energy);
        else if (it < NITER - 1)
            pc_gemm<0><<<dim3(BATCH / BM, 16), 512, 0, stream>>>(
                src, nullptr, nullptr, wg, wc, xbf, bias_gen, bias_out,
                dst, u, z, ey, nullptr, energy);
        else
            pc_gemm<2><<<dim3(BATCH / BM, 8), 512, 0, stream>>>(
                src, nullptr, nullptr, wg, wc, xbf, bias_gen, bias_out,
                nullptr, u, z, ey, y, energy);
    }
    finalize_kernel<<<1, 1, 0, stream>>>(energy, y + (size_t)BATCH * DOUT);
}